// Round 5
// baseline (483.329 us; speedup 1.0000x reference)
//
#include <hip/hip_runtime.h>
#include <hip/hip_bf16.h>

#define N_NODES 100000
#define D 128
#define N_REL 4
#define N_EDGES 500000
#define N_CNT (N_REL * N_NODES)                                  // 400,000
#define SCAN_CHUNK 1024
#define N_SCAN_BLK ((N_CNT + SCAN_CHUNK - 1) / SCAN_CHUNK)       // 391
#define SORT_MAX (N_REL * N_EDGES + 3 * N_CNT)                   // padded sort capacity: 3.2M

typedef __attribute__((ext_vector_type(8))) short bf16x8;
typedef __attribute__((ext_vector_type(4))) float f32x4;

__device__ __forceinline__ unsigned short f2bf(float f) {
    unsigned int u = __float_as_uint(f);
    u += 0x7fffu + ((u >> 16) & 1u);
    return (unsigned short)(u >> 16);
}

// ---------------- prep: x->bf16 cvt | zero row | W^T build (bf16) | per-(rel,tgt) histogram
#define CVT_BLOCKS 6250    // 8 floats/thread * 256
#define WB_BLOCKS 320      // 81920 elems / 256
#define ZR_BLOCKS 1
#define HIST_BLOCKS 7813
__global__ __launch_bounds__(256) void prep_kernel(const float* __restrict__ x,
                                                   const int* __restrict__ ei,
                                                   const float* __restrict__ W,
                                                   const float* __restrict__ W_sl,
                                                   ushort* __restrict__ xbf,
                                                   ushort* __restrict__ WbT,
                                                   int* __restrict__ cnt) {
    const int b = blockIdx.x, tid = threadIdx.x;
    if (b < CVT_BLOCKS) {
        size_t t = (size_t)b * 256 + tid;                 // one int4 (8 bf16) per thread
        float4 v0 = ((const float4*)x)[t * 2];
        float4 v1 = ((const float4*)x)[t * 2 + 1];
        int4 o;
        o.x = ((int)f2bf(v0.y) << 16) | f2bf(v0.x);
        o.y = ((int)f2bf(v0.w) << 16) | f2bf(v0.z);
        o.z = ((int)f2bf(v1.y) << 16) | f2bf(v1.x);
        o.w = ((int)f2bf(v1.w) << 16) | f2bf(v1.z);
        ((int4*)xbf)[t] = o;
    } else if (b < CVT_BLOCKS + WB_BLOCKS) {
        // WbT[f][k], k = r*128+d (k<512) -> W[r][f][d]; k in [512,640) -> W_sl[f][k-512]
        int t = (b - CVT_BLOCKS) * 256 + tid;             // 0..81919
        int f = t / 640;
        int k = t - f * 640;
        float v;
        if (k < 512) {
            int r = k >> 7, d = k & 127;
            v = W[((size_t)r * 128 + f) * 128 + d];
        } else {
            v = W_sl[(size_t)f * 128 + (k - 512)];
        }
        WbT[t] = f2bf(v);
    } else if (b < CVT_BLOCKS + WB_BLOCKS + ZR_BLOCKS) {
        // sentinel zero row xbf[N_NODES][*]
        if (tid < 16) ((uint4*)(xbf + (size_t)N_NODES * D))[tid] = make_uint4(0, 0, 0, 0);
    } else {
        int t = (b - CVT_BLOCKS - WB_BLOCKS - ZR_BLOCKS) * 256 + tid;
        if (t >= N_REL * N_EDGES) return;
        int r = t / N_EDGES;
        int e = t - r * N_EDGES;
        int tgt = ei[(size_t)r * 2 * N_EDGES + N_EDGES + e];
        atomicAdd(&cnt[r * N_NODES + tgt], 1);
    }
}

// ---------------- scanA: per-chunk local prefix of PADDED counts -> foff(local), chunk totals
__global__ __launch_bounds__(256) void scanA(const int* __restrict__ cnt,
                                             int* __restrict__ foff,
                                             int* __restrict__ partials) {
    __shared__ int ps[256];
    int b = blockIdx.x, t = threadIdx.x;
    int i0 = b * SCAN_CHUNK + t * 4;
    int v[4];
#pragma unroll
    for (int q = 0; q < 4; ++q) v[q] = (i0 + q < N_CNT) ? ((cnt[i0 + q] + 3) & ~3) : 0;
    int s = v[0] + v[1] + v[2] + v[3];
    ps[t] = s;
    __syncthreads();
    for (int d = 1; d < 256; d <<= 1) {
        int u = (t >= d) ? ps[t - d] : 0;
        __syncthreads();
        ps[t] += u;
        __syncthreads();
    }
    if (t == 255) partials[b] = ps[255];
    int run = (t == 0) ? 0 : ps[t - 1];
#pragma unroll
    for (int q = 0; q < 4; ++q) {
        if (i0 + q < N_CNT) foff[i0 + q] = run;
        run += v[q];
    }
}
// ---------------- scanB: scan chunk totals; write grand total to foff[N_CNT]
__global__ __launch_bounds__(512) void scanB(int* __restrict__ partials,
                                             int* __restrict__ foff) {
    __shared__ int ps[512];
    int t = threadIdx.x;
    ps[t] = (t < N_SCAN_BLK) ? partials[t] : 0;
    __syncthreads();
    for (int d = 1; d < 512; d <<= 1) {
        int u = (t >= d) ? ps[t - d] : 0;
        __syncthreads();
        ps[t] += u;
        __syncthreads();
    }
    if (t < N_SCAN_BLK) partials[t] = (t == 0) ? 0 : ps[t - 1];
    if (t == N_SCAN_BLK - 1) foff[N_CNT] = ps[t];
}
// ---------------- scanC: foff += partials (global base); zero cur0; sentinel-fill pad slots
__global__ __launch_bounds__(256) void scanC(int* __restrict__ foff,
                                             const int* __restrict__ partials,
                                             const int* __restrict__ cnt,
                                             int* __restrict__ cur0,
                                             int* __restrict__ sorted) {
    int i = blockIdx.x * 256 + threadIdx.x;
    if (i >= N_CNT) return;
    int base = foff[i] + partials[i >> 10];
    foff[i] = base;
    cur0[i] = 0;
    int c = cnt[i];
    int cp = (c + 3) & ~3;
    for (int j = c; j < cp; ++j) sorted[base + j] = N_NODES;
}

// ---------------- scatter src into (rel,tgt)-sorted padded order
__global__ __launch_bounds__(256) void bucket_kernel(const int* __restrict__ ei,
                                                     const int* __restrict__ foff,
                                                     int* __restrict__ cur0,
                                                     int* __restrict__ sorted) {
    int t = blockIdx.x * 256 + threadIdx.x;
    if (t >= N_REL * N_EDGES) return;
    int r = t / N_EDGES;
    int e = t - r * N_EDGES;
    int src = ei[(size_t)r * 2 * N_EDGES + e];
    int tgt = ei[(size_t)r * 2 * N_EDGES + N_EDGES + e];
    int i = r * N_NODES + tgt;
    int pos = foff[i] + atomicAdd(&cur0[i], 1);
    sorted[pos] = src;
}

// ---------------- gather: one wave per 4 consecutive (rel,node) pairs.
// Edge lists are contiguous & 4-padded: inner loop = 1 uniform int4 (4 srcs) + 4 row gathers.
__global__ __launch_bounds__(256) void gather_kernel(const ushort* __restrict__ xbf,
                                                     const int* __restrict__ sorted,
                                                     const int* __restrict__ foff,
                                                     unsigned int* __restrict__ buf) {
    int wid = (blockIdx.x * 256 + threadIdx.x) >> 6;
    wid = __builtin_amdgcn_readfirstlane(wid);
    const int lane = threadIdx.x & 63;
    const int p0 = wid * 4;
    int f0 = foff[p0], f1 = foff[p0 + 1], f2 = foff[p0 + 2], f3 = foff[p0 + 3], f4 = foff[p0 + 4];
#pragma unroll
    for (int pi = 0; pi < 4; ++pi) {
        int gb = (pi == 0) ? f0 : (pi == 1) ? f1 : (pi == 2) ? f2 : f3;
        int ge = (pi == 0) ? f1 : (pi == 1) ? f2 : (pi == 2) ? f3 : f4;
        float ax = 0.f, ay = 0.f;
        for (int g = gb; g < ge; g += 4) {
            int4 s = *(const int4*)(sorted + g);
            unsigned int u0 = ((const unsigned int*)(xbf + ((size_t)s.x << 7)))[lane];
            unsigned int u1 = ((const unsigned int*)(xbf + ((size_t)s.y << 7)))[lane];
            unsigned int u2 = ((const unsigned int*)(xbf + ((size_t)s.z << 7)))[lane];
            unsigned int u3 = ((const unsigned int*)(xbf + ((size_t)s.w << 7)))[lane];
            ax += __uint_as_float(u0 << 16) + __uint_as_float(u1 << 16)
                + __uint_as_float(u2 << 16) + __uint_as_float(u3 << 16);
            ay += __uint_as_float(u0 & 0xffff0000u) + __uint_as_float(u1 & 0xffff0000u)
                + __uint_as_float(u2 & 0xffff0000u) + __uint_as_float(u3 & 0xffff0000u);
        }
        buf[(size_t)(p0 + pi) * 64 + lane] = ((unsigned int)f2bf(ay) << 16) | f2bf(ax);
    }
}

// ---------------- MFMA GEMM: out[100000][128] = A[100000][640]bf16 @ B[640][128]bf16 + bias
// 128x128 tile, 4 waves (2x2), 16x16x32 mfma, reg-prefetch double-buffered staging.
__global__ __launch_bounds__(256) void gemm_kernel(const ushort* __restrict__ buf,
                                                   const ushort* __restrict__ xbf,
                                                   const ushort* __restrict__ WbT,
                                                   const int* __restrict__ cnt,
                                                   const float* __restrict__ bias,
                                                   const float* __restrict__ b_sl,
                                                   float* __restrict__ out) {
    __shared__ __align__(16) ushort As[128 * 72];   // [row][k] pad 64->72
    __shared__ __align__(16) ushort Bs[128 * 72];   // [f][k]
    __shared__ float degS[4 * 128];
    __shared__ float biasS[4 * 128];
    __shared__ float bslS[128];

    const int tid = threadIdx.x;
    const int l = tid & 63, w = tid >> 6;
    const int wr = w >> 1, wc = w & 1;
    const int lr = l & 15, lq = l >> 4;
    const int n0 = blockIdx.x * 128;

#pragma unroll
    for (int it = 0; it < 2; ++it) {
        int idx = it * 256 + tid;
        int r = idx >> 7, row = idx & 127;
        int n = n0 + row;
        degS[idx] = (n < N_NODES) ? (float)cnt[r * N_NODES + n] : 0.f;
        biasS[idx] = bias[idx];
    }
    if (tid < 128) bslS[tid] = b_sl[tid];

    f32x4 acc[4][4];
#pragma unroll
    for (int mi = 0; mi < 4; ++mi)
#pragma unroll
        for (int ni = 0; ni < 4; ++ni) acc[mi][ni] = (f32x4){0.f, 0.f, 0.f, 0.f};

    // per-thread staging coords
    const int ar_ = (tid * 4) >> 3 >> 0;  // unused placeholder to keep names clear
    int4 aReg[4], bReg[4];

    auto LOAD = [&](int kt) {
        const int region = kt >> 1;
        const int d0 = (kt & 1) * 64;
#pragma unroll
        for (int it = 0; it < 4; ++it) {
            int id = it * 256 + tid;
            int r_ = id >> 3, c16 = id & 7;
            int n = n0 + r_;
            if (n > N_NODES - 1) n = N_NODES - 1;
            const ushort* sp = (region < 4)
                ? ((const ushort*)buf + (((size_t)region * N_NODES + n) << 7) + d0)
                : (xbf + ((size_t)n << 7) + d0);
            aReg[it] = *(const int4*)(sp + c16 * 8);
        }
#pragma unroll
        for (int it = 0; it < 4; ++it) {
            int id = it * 256 + tid;
            int f_ = id >> 3, c16 = id & 7;
            bReg[it] = *(const int4*)(WbT + (size_t)f_ * 640 + kt * 64 + c16 * 8);
        }
    };

    LOAD(0);
    for (int kt = 0; kt < 10; ++kt) {
        __syncthreads();   // LDS free (prev readers done); kt==0 also covers deg/bias staging
#pragma unroll
        for (int it = 0; it < 4; ++it) {
            int id = it * 256 + tid;
            int r_ = id >> 3, c16 = id & 7;
            *(int4*)(As + r_ * 72 + c16 * 8) = aReg[it];
            *(int4*)(Bs + r_ * 72 + c16 * 8) = bReg[it];
        }
        __syncthreads();   // LDS ready
        if (kt < 9) LOAD(kt + 1);   // prefetch overlaps MFMA below
#pragma unroll
        for (int ks = 0; ks < 2; ++ks) {
            bf16x8 a[4], bb[4];
#pragma unroll
            for (int mi = 0; mi < 4; ++mi)
                a[mi] = *(const bf16x8*)(As + (wr * 64 + mi * 16 + lr) * 72 + ks * 32 + lq * 8);
#pragma unroll
            for (int ni = 0; ni < 4; ++ni)
                bb[ni] = *(const bf16x8*)(Bs + (wc * 64 + ni * 16 + lr) * 72 + ks * 32 + lq * 8);
#pragma unroll
            for (int mi = 0; mi < 4; ++mi)
#pragma unroll
                for (int ni = 0; ni < 4; ++ni)
                    acc[mi][ni] = __builtin_amdgcn_mfma_f32_16x16x32_bf16(a[mi], bb[ni], acc[mi][ni], 0, 0, 0);
        }
    }

    // epilogue: C/D frag layout col=lane&15, row=(lane>>4)*4+q
    float bw[4][4], bsl_[4];
#pragma unroll
    for (int ni = 0; ni < 4; ++ni) {
        int f = wc * 64 + ni * 16 + lr;
        bsl_[ni] = bslS[f];
#pragma unroll
        for (int r = 0; r < 4; ++r) bw[ni][r] = biasS[r * 128 + f];
    }
#pragma unroll
    for (int mi = 0; mi < 4; ++mi) {
#pragma unroll
        for (int q = 0; q < 4; ++q) {
            int row = wr * 64 + mi * 16 + lq * 4 + q;
            int n = n0 + row;
            if (n >= N_NODES) continue;
            float d0_ = degS[row], d1_ = degS[128 + row], d2_ = degS[256 + row], d3_ = degS[384 + row];
#pragma unroll
            for (int ni = 0; ni < 4; ++ni) {
                int f = wc * 64 + ni * 16 + lr;
                float v = acc[mi][ni][q] + d0_ * bw[ni][0] + d1_ * bw[ni][1]
                        + d2_ * bw[ni][2] + d3_ * bw[ni][3] + bsl_[ni];
                out[(size_t)n * 128 + f] = v;
            }
        }
    }
}

extern "C" void kernel_launch(void* const* d_in, const int* in_sizes, int n_in,
                              void* d_out, int out_size, void* d_ws, size_t ws_size,
                              hipStream_t stream) {
    const float* x    = (const float*)d_in[0];
    const int*   ei   = (const int*)d_in[1];
    const float* W    = (const float*)d_in[2];
    const float* b    = (const float*)d_in[3];
    const float* W_sl = (const float*)d_in[4];
    const float* b_sl = (const float*)d_in[5];
    float* out = (float*)d_out;

    // ws layout (~148 MB), 256B-aligned chunks
    int*          cnt      = (int*)d_ws;                          // 400000
    int*          cur0     = cnt + N_CNT;                         // 400000
    int*          foff     = cur0 + N_CNT;                        // 400001 (+pad)
    int*          partials = foff + N_CNT + 64;                   // 512
    ushort*       WbT      = (ushort*)(partials + 512);           // 128*640
    ushort*       xbf      = WbT + 128 * 640;                     // (100001)*128
    int*          sorted   = (int*)(xbf + (size_t)(N_NODES + 1) * D + 64);  // up to 3.2M
    unsigned int* buf      = (unsigned int*)(sorted + SORT_MAX);  // 400000*64 uints

    hipMemsetAsync(cnt, 0, N_CNT * sizeof(int), stream);

    prep_kernel<<<CVT_BLOCKS + WB_BLOCKS + ZR_BLOCKS + HIST_BLOCKS, 256, 0, stream>>>(
        x, ei, W, W_sl, xbf, WbT, cnt);
    scanA<<<N_SCAN_BLK, 256, 0, stream>>>(cnt, foff, partials);
    scanB<<<1, 512, 0, stream>>>(partials, foff);
    scanC<<<(N_CNT + 255) / 256, 256, 0, stream>>>(foff, partials, cnt, cur0, sorted);
    bucket_kernel<<<(N_REL * N_EDGES + 255) / 256, 256, 0, stream>>>(ei, foff, cur0, sorted);
    gather_kernel<<<N_CNT / 16, 256, 0, stream>>>(xbf, sorted, foff, buf);
    gemm_kernel<<<(N_NODES + 127) / 128, 256, 0, stream>>>((const ushort*)buf, xbf, WbT, cnt, b, b_sl, out);
}

// Round 6
// 415.150 us; speedup vs baseline: 1.1642x; 1.1642x over previous
//
#include <hip/hip_runtime.h>
#include <hip/hip_bf16.h>

#define N_NODES 100000
#define D 128
#define N_REL 4
#define N_EDGES 500000
#define N_CNT (N_REL * N_NODES)                                  // 400,000
#define SCAN_CHUNK 1024
#define N_SCAN_BLK ((N_CNT + SCAN_CHUNK - 1) / SCAN_CHUNK)       // 391
#define SORT_MAX (N_REL * N_EDGES + 3 * N_CNT)                   // padded sort capacity: 3.2M

typedef __attribute__((ext_vector_type(8))) short bf16x8;
typedef __attribute__((ext_vector_type(4))) float f32x4;

__device__ __forceinline__ unsigned short f2bf(float f) {
    unsigned int u = __float_as_uint(f);
    u += 0x7fffu + ((u >> 16) & 1u);
    return (unsigned short)(u >> 16);
}

// ---------------- prep: x->bf16 cvt | zero row | W^T build (bf16) | per-(rel,tgt) histogram
#define CVT_BLOCKS 6250    // 8 floats/thread * 256
#define WB_BLOCKS 320      // 81920 elems / 256
#define ZR_BLOCKS 1
#define HIST_BLOCKS 7813
__global__ __launch_bounds__(256) void prep_kernel(const float* __restrict__ x,
                                                   const int* __restrict__ ei,
                                                   const float* __restrict__ W,
                                                   const float* __restrict__ W_sl,
                                                   ushort* __restrict__ xbf,
                                                   ushort* __restrict__ WbT,
                                                   int* __restrict__ cnt) {
    const int b = blockIdx.x, tid = threadIdx.x;
    if (b < CVT_BLOCKS) {
        size_t t = (size_t)b * 256 + tid;                 // one int4 (8 bf16) per thread
        float4 v0 = ((const float4*)x)[t * 2];
        float4 v1 = ((const float4*)x)[t * 2 + 1];
        int4 o;
        o.x = ((int)f2bf(v0.y) << 16) | f2bf(v0.x);
        o.y = ((int)f2bf(v0.w) << 16) | f2bf(v0.z);
        o.z = ((int)f2bf(v1.y) << 16) | f2bf(v1.x);
        o.w = ((int)f2bf(v1.w) << 16) | f2bf(v1.z);
        ((int4*)xbf)[t] = o;
    } else if (b < CVT_BLOCKS + WB_BLOCKS) {
        // WbT[f][k], k = r*128+d (k<512) -> W[r][f][d]; k in [512,640) -> W_sl[f][k-512]
        int t = (b - CVT_BLOCKS) * 256 + tid;             // 0..81919
        int f = t / 640;
        int k = t - f * 640;
        float v;
        if (k < 512) {
            int r = k >> 7, d = k & 127;
            v = W[((size_t)r * 128 + f) * 128 + d];
        } else {
            v = W_sl[(size_t)f * 128 + (k - 512)];
        }
        WbT[t] = f2bf(v);
    } else if (b < CVT_BLOCKS + WB_BLOCKS + ZR_BLOCKS) {
        // sentinel zero row xbf[N_NODES][*]
        if (tid < 16) ((uint4*)(xbf + (size_t)N_NODES * D))[tid] = make_uint4(0, 0, 0, 0);
    } else {
        int t = (b - CVT_BLOCKS - WB_BLOCKS - ZR_BLOCKS) * 256 + tid;
        if (t >= N_REL * N_EDGES) return;
        int r = t / N_EDGES;
        int e = t - r * N_EDGES;
        int tgt = ei[(size_t)r * 2 * N_EDGES + N_EDGES + e];
        atomicAdd(&cnt[r * N_NODES + tgt], 1);
    }
}

// ---------------- scanA: per-chunk local prefix of PADDED counts -> foff(local), raw chunk totals
__global__ __launch_bounds__(256) void scanA(const int* __restrict__ cnt,
                                             int* __restrict__ foff,
                                             int* __restrict__ partials) {
    __shared__ int ps[256];
    int b = blockIdx.x, t = threadIdx.x;
    int i0 = b * SCAN_CHUNK + t * 4;
    int v[4];
#pragma unroll
    for (int q = 0; q < 4; ++q) v[q] = (i0 + q < N_CNT) ? ((cnt[i0 + q] + 3) & ~3) : 0;
    int s = v[0] + v[1] + v[2] + v[3];
    ps[t] = s;
    __syncthreads();
    for (int d = 1; d < 256; d <<= 1) {
        int u = (t >= d) ? ps[t - d] : 0;
        __syncthreads();
        ps[t] += u;
        __syncthreads();
    }
    if (t == 255) partials[b] = ps[255];
    int run = (t == 0) ? 0 : ps[t - 1];
#pragma unroll
    for (int q = 0; q < 4; ++q) {
        if (i0 + q < N_CNT) foff[i0 + q] = run;
        run += v[q];
    }
}

// ---------------- scanC: globalize foff (each block reduces needed partials itself);
// zero cur0; sentinel-fill pad slots; last thread writes grand total to foff[N_CNT].
__global__ __launch_bounds__(256) void scanC(int* __restrict__ foff,
                                             const int* __restrict__ partials,
                                             const int* __restrict__ cnt,
                                             int* __restrict__ cur0,
                                             int* __restrict__ sorted) {
    __shared__ int red[256];
    const int b = blockIdx.x, t = threadIdx.x;
    const int pb = b >> 2;                 // this block's 256 i's all live in chunk b>>2
    int s = 0;
    for (int j = t; j < pb; j += 256) s += partials[j];
    red[t] = s;
    __syncthreads();
    for (int d = 128; d > 0; d >>= 1) {
        if (t < d) red[t] += red[t + d];
        __syncthreads();
    }
    const int P = red[0];
    int i = b * 256 + t;
    if (i >= N_CNT) return;
    int base = foff[i] + P;
    foff[i] = base;
    cur0[i] = 0;
    int c = cnt[i];
    int cp = (c + 3) & ~3;
    for (int j = c; j < cp; ++j) sorted[base + j] = N_NODES;
    if (i == N_CNT - 1) foff[N_CNT] = base + cp;
}

// ---------------- scatter src into (rel,tgt)-sorted padded order
__global__ __launch_bounds__(256) void bucket_kernel(const int* __restrict__ ei,
                                                     const int* __restrict__ foff,
                                                     int* __restrict__ cur0,
                                                     int* __restrict__ sorted) {
    int t = blockIdx.x * 256 + threadIdx.x;
    if (t >= N_REL * N_EDGES) return;
    int r = t / N_EDGES;
    int e = t - r * N_EDGES;
    int src = ei[(size_t)r * 2 * N_EDGES + e];
    int tgt = ei[(size_t)r * 2 * N_EDGES + N_EDGES + e];
    int i = r * N_NODES + tgt;
    int pos = foff[i] + atomicAdd(&cur0[i], 1);
    sorted[pos] = src;
}

// ---------------- gather: one wave per 4 consecutive (rel,node) pairs.
// Edge lists contiguous & 4-padded: inner loop = 1 uniform int4 (4 srcs) + 4 row gathers.
__global__ __launch_bounds__(256) void gather_kernel(const ushort* __restrict__ xbf,
                                                     const int* __restrict__ sorted,
                                                     const int* __restrict__ foff,
                                                     unsigned int* __restrict__ buf) {
    int wid = (blockIdx.x * 256 + threadIdx.x) >> 6;
    wid = __builtin_amdgcn_readfirstlane(wid);
    const int lane = threadIdx.x & 63;
    const int p0 = wid * 4;
    int f0 = foff[p0], f1 = foff[p0 + 1], f2 = foff[p0 + 2], f3 = foff[p0 + 3], f4 = foff[p0 + 4];
#pragma unroll
    for (int pi = 0; pi < 4; ++pi) {
        int gb = (pi == 0) ? f0 : (pi == 1) ? f1 : (pi == 2) ? f2 : f3;
        int ge = (pi == 0) ? f1 : (pi == 1) ? f2 : (pi == 2) ? f3 : f4;
        float ax = 0.f, ay = 0.f;
        for (int g = gb; g < ge; g += 4) {
            int4 s = *(const int4*)(sorted + g);
            unsigned int u0 = ((const unsigned int*)(xbf + ((size_t)s.x << 7)))[lane];
            unsigned int u1 = ((const unsigned int*)(xbf + ((size_t)s.y << 7)))[lane];
            unsigned int u2 = ((const unsigned int*)(xbf + ((size_t)s.z << 7)))[lane];
            unsigned int u3 = ((const unsigned int*)(xbf + ((size_t)s.w << 7)))[lane];
            ax += __uint_as_float(u0 << 16) + __uint_as_float(u1 << 16)
                + __uint_as_float(u2 << 16) + __uint_as_float(u3 << 16);
            ay += __uint_as_float(u0 & 0xffff0000u) + __uint_as_float(u1 & 0xffff0000u)
                + __uint_as_float(u2 & 0xffff0000u) + __uint_as_float(u3 & 0xffff0000u);
        }
        buf[(size_t)(p0 + pi) * 64 + lane] = ((unsigned int)f2bf(ay) << 16) | f2bf(ax);
    }
}

// ---------------- MFMA GEMM: out[100000][128] = A[100000][640]bf16 @ B[640][128]bf16 + bias
// 128x128 tile, 4 waves (2x2), 16x16x32 mfma. XOR-swizzled LDS (stride 64, chunk^row&7);
// epilogue staged through LDS (stride 132) for fully-coalesced float4 output lines.
__global__ __launch_bounds__(256) void gemm_kernel(const ushort* __restrict__ buf,
                                                   const ushort* __restrict__ xbf,
                                                   const ushort* __restrict__ WbT,
                                                   const int* __restrict__ cnt,
                                                   const float* __restrict__ bias,
                                                   const float* __restrict__ b_sl,
                                                   float* __restrict__ out) {
    __shared__ __align__(16) float SH[64 * 132];   // 33.8 KB: A/B bf16 tiles OR C f32 stage
    __shared__ float degS[4 * 128];
    __shared__ float biasS[4 * 128];
    __shared__ float bslS[128];
    ushort* As = (ushort*)SH;          // [128][64] swizzled
    ushort* Bs = As + 128 * 64;        // [128][64] swizzled

    const int tid = threadIdx.x;
    const int l = tid & 63, w = tid >> 6;
    const int wr = w >> 1, wc = w & 1;
    const int lr = l & 15, lq = l >> 4;
    const int n0 = blockIdx.x * 128;

#pragma unroll
    for (int it = 0; it < 2; ++it) {
        int idx = it * 256 + tid;
        int r = idx >> 7, row = idx & 127;
        int n = n0 + row;
        degS[idx] = (n < N_NODES) ? (float)cnt[r * N_NODES + n] : 0.f;
        biasS[idx] = bias[idx];
    }
    if (tid < 128) bslS[tid] = b_sl[tid];

    f32x4 acc[4][4];
#pragma unroll
    for (int mi = 0; mi < 4; ++mi)
#pragma unroll
        for (int ni = 0; ni < 4; ++ni) acc[mi][ni] = (f32x4){0.f, 0.f, 0.f, 0.f};

    for (int kt = 0; kt < 10; ++kt) {
        __syncthreads();   // LDS free (prev readers done); kt==0 also covers deg/bias staging
        const int region = kt >> 1;
        const int d0 = (kt & 1) * 64;
#pragma unroll
        for (int it = 0; it < 4; ++it) {
            int id = it * 256 + tid;
            int r_ = id >> 3, c16 = id & 7;
            int n = n0 + r_;
            if (n > N_NODES - 1) n = N_NODES - 1;   // clamp keeps loads in-bounds
            const ushort* sp = (region < 4)
                ? (buf + (((size_t)region * N_NODES + n) << 7) + d0)
                : (xbf + ((size_t)n << 7) + d0);
            int4 va = *(const int4*)(sp + c16 * 8);
            *(int4*)(As + r_ * 64 + ((c16 ^ (r_ & 7)) << 3)) = va;
            int4 vb = *(const int4*)(WbT + (size_t)r_ * 640 + kt * 64 + c16 * 8);
            *(int4*)(Bs + r_ * 64 + ((c16 ^ (r_ & 7)) << 3)) = vb;
        }
        __syncthreads();
#pragma unroll
        for (int ks = 0; ks < 2; ++ks) {
            const int ch = ks * 4 + lq;
            const int chs = (ch ^ (lr & 7)) << 3;
            bf16x8 a[4], bb[4];
#pragma unroll
            for (int mi = 0; mi < 4; ++mi)
                a[mi] = *(const bf16x8*)(As + (wr * 64 + mi * 16 + lr) * 64 + chs);
#pragma unroll
            for (int ni = 0; ni < 4; ++ni)
                bb[ni] = *(const bf16x8*)(Bs + (wc * 64 + ni * 16 + lr) * 64 + chs);
#pragma unroll
            for (int mi = 0; mi < 4; ++mi)
#pragma unroll
                for (int ni = 0; ni < 4; ++ni)
                    acc[mi][ni] = __builtin_amdgcn_mfma_f32_16x16x32_bf16(a[mi], bb[ni], acc[mi][ni], 0, 0, 0);
        }
    }

    // epilogue: frag layout col=lane&15, row=(lane>>4)*4+q. Stage through LDS, float4 out.
    float bw[4][4], bsl_[4];
#pragma unroll
    for (int ni = 0; ni < 4; ++ni) {
        int f = wc * 64 + ni * 16 + lr;
        bsl_[ni] = bslS[f];
#pragma unroll
        for (int r = 0; r < 4; ++r) bw[ni][r] = biasS[r * 128 + f];
    }
    float* Cs = SH;   // [64][132]
#pragma unroll
    for (int h = 0; h < 2; ++h) {
        __syncthreads();   // A/B tile (or prev half) readers done
        if (wr == h) {
#pragma unroll
            for (int mi = 0; mi < 4; ++mi)
#pragma unroll
                for (int q = 0; q < 4; ++q) {
                    int row = mi * 16 + lq * 4 + q;          // 0..63
                    int gr = h * 64 + row;
                    float d0_ = degS[gr], d1_ = degS[128 + gr], d2_ = degS[256 + gr], d3_ = degS[384 + gr];
#pragma unroll
                    for (int ni = 0; ni < 4; ++ni) {
                        int f = wc * 64 + ni * 16 + lr;
                        Cs[row * 132 + f] = acc[mi][ni][q] + d0_ * bw[ni][0] + d1_ * bw[ni][1]
                                          + d2_ * bw[ni][2] + d3_ * bw[ni][3] + bsl_[ni];
                    }
                }
        }
        __syncthreads();
#pragma unroll
        for (int it = 0; it < 8; ++it) {
            int idx = it * 256 + tid;        // 0..2047
            int row = idx >> 5, c4 = idx & 31;
            int n = n0 + h * 64 + row;
            if (n < N_NODES)
                *(float4*)(out + (size_t)n * 128 + c4 * 4) = *(const float4*)(Cs + row * 132 + c4 * 4);
        }
    }
}

extern "C" void kernel_launch(void* const* d_in, const int* in_sizes, int n_in,
                              void* d_out, int out_size, void* d_ws, size_t ws_size,
                              hipStream_t stream) {
    const float* x    = (const float*)d_in[0];
    const int*   ei   = (const int*)d_in[1];
    const float* W    = (const float*)d_in[2];
    const float* b    = (const float*)d_in[3];
    const float* W_sl = (const float*)d_in[4];
    const float* b_sl = (const float*)d_in[5];
    float* out = (float*)d_out;

    // ws layout (~148 MB), 256B-aligned chunks
    int*          cnt      = (int*)d_ws;                          // 400000
    int*          cur0     = cnt + N_CNT;                         // 400000
    int*          foff     = cur0 + N_CNT;                        // 400001 (+pad)
    int*          partials = foff + N_CNT + 64;                   // 391 (+pad)
    ushort*       WbT      = (ushort*)(partials + 512);           // 128*640
    ushort*       xbf      = WbT + 128 * 640;                     // (100001)*128
    int*          sorted   = (int*)(xbf + (size_t)(N_NODES + 1) * D + 64);  // up to 3.2M
    unsigned int* buf      = (unsigned int*)(sorted + SORT_MAX);  // 400000*64 uints

    hipMemsetAsync(cnt, 0, N_CNT * sizeof(int), stream);

    prep_kernel<<<CVT_BLOCKS + WB_BLOCKS + ZR_BLOCKS + HIST_BLOCKS, 256, 0, stream>>>(
        x, ei, W, W_sl, xbf, WbT, cnt);
    scanA<<<N_SCAN_BLK, 256, 0, stream>>>(cnt, foff, partials);
    scanC<<<(N_CNT + 255) / 256, 256, 0, stream>>>(foff, partials, cnt, cur0, sorted);
    bucket_kernel<<<(N_REL * N_EDGES + 255) / 256, 256, 0, stream>>>(ei, foff, cur0, sorted);
    gather_kernel<<<N_CNT / 16, 256, 0, stream>>>(xbf, sorted, foff, buf);
    gemm_kernel<<<(N_NODES + 127) / 128, 256, 0, stream>>>((const ushort*)buf, xbf, WbT, cnt, b, b_sl, out);
}

// Round 8
// 402.745 us; speedup vs baseline: 1.2001x; 1.0308x over previous
//
#include <hip/hip_runtime.h>
#include <hip/hip_bf16.h>

#define N_NODES 100000
#define D 128
#define N_REL 4
#define N_EDGES 500000
#define N_CNT (N_REL * N_NODES)                                  // 400,000
#define SCAN_CHUNK 1024
#define N_SCAN_BLK ((N_CNT + SCAN_CHUNK - 1) / SCAN_CHUNK)       // 391
#define SORT_MAX (N_REL * N_EDGES + 3 * N_CNT)                   // padded sort capacity: 3.2M
#define NXCD 8
#define NODES_PER_XCD (N_NODES / NXCD)                           // 12500

typedef __attribute__((ext_vector_type(8))) short bf16x8;
typedef __attribute__((ext_vector_type(4))) float f32x4;

__device__ __forceinline__ unsigned short f2bf(float f) {
    unsigned int u = __float_as_uint(f);
    u += 0x7fffu + ((u >> 16) & 1u);
    return (unsigned short)(u >> 16);
}

// ---------------- prep: x->bf16 cvt | zero row | W^T build (bf16) | per-(rel,tgt) histogram
// hist is XCD-ownership partitioned: block class (hb&7) handles one 12500-node tgt range,
// so each XCD's atomics hit an XCD-private 200 KB window of cnt.
#define CVT_BLOCKS 6250    // 8 floats/thread * 256
#define WB_BLOCKS 320      // 81920 elems / 256
#define ZR_BLOCKS 1
#define HIST_BLOCKS (7813 * NXCD)
__global__ __launch_bounds__(256) void prep_kernel(const float* __restrict__ x,
                                                   const int* __restrict__ ei,
                                                   const float* __restrict__ W,
                                                   const float* __restrict__ W_sl,
                                                   ushort* __restrict__ xbf,
                                                   ushort* __restrict__ WbT,
                                                   int* __restrict__ cnt) {
    const int b = blockIdx.x, tid = threadIdx.x;
    if (b < CVT_BLOCKS) {
        size_t t = (size_t)b * 256 + tid;                 // one int4 (8 bf16) per thread
        float4 v0 = ((const float4*)x)[t * 2];
        float4 v1 = ((const float4*)x)[t * 2 + 1];
        int4 o;
        o.x = ((int)f2bf(v0.y) << 16) | f2bf(v0.x);
        o.y = ((int)f2bf(v0.w) << 16) | f2bf(v0.z);
        o.z = ((int)f2bf(v1.y) << 16) | f2bf(v1.x);
        o.w = ((int)f2bf(v1.w) << 16) | f2bf(v1.z);
        ((int4*)xbf)[t] = o;
    } else if (b < CVT_BLOCKS + WB_BLOCKS) {
        // WbT[f][k], k = r*128+d (k<512) -> W[r][f][d]; k in [512,640) -> W_sl[f][k-512]
        int t = (b - CVT_BLOCKS) * 256 + tid;             // 0..81919
        int f = t / 640;
        int k = t - f * 640;
        float v;
        if (k < 512) {
            int r = k >> 7, d = k & 127;
            v = W[((size_t)r * 128 + f) * 128 + d];
        } else {
            v = W_sl[(size_t)f * 128 + (k - 512)];
        }
        WbT[t] = f2bf(v);
    } else if (b < CVT_BLOCKS + WB_BLOCKS + ZR_BLOCKS) {
        // sentinel zero row xbf[N_NODES][*]
        if (tid < 16) ((uint4*)(xbf + (size_t)N_NODES * D))[tid] = make_uint4(0, 0, 0, 0);
    } else {
        int hb = b - CVT_BLOCKS - WB_BLOCKS - ZR_BLOCKS;  // 0..HIST_BLOCKS-1
        int xcd = hb & 7;
        int t = (hb >> 3) * 256 + tid;
        if (t >= N_REL * N_EDGES) return;
        int r = t / N_EDGES;
        int e = t - r * N_EDGES;
        int tgt = ei[(size_t)r * 2 * N_EDGES + N_EDGES + e];
        if ((unsigned)(tgt - xcd * NODES_PER_XCD) < (unsigned)NODES_PER_XCD)
            atomicAdd(&cnt[r * N_NODES + tgt], 1);
    }
}

// ---------------- scanA: per-chunk local prefix of PADDED counts -> foff(local), raw chunk totals
__global__ __launch_bounds__(256) void scanA(const int* __restrict__ cnt,
                                             int* __restrict__ foff,
                                             int* __restrict__ partials) {
    __shared__ int ps[256];
    int b = blockIdx.x, t = threadIdx.x;
    int i0 = b * SCAN_CHUNK + t * 4;
    int v[4];
#pragma unroll
    for (int q = 0; q < 4; ++q) v[q] = (i0 + q < N_CNT) ? ((cnt[i0 + q] + 3) & ~3) : 0;
    int s = v[0] + v[1] + v[2] + v[3];
    ps[t] = s;
    __syncthreads();
    for (int d = 1; d < 256; d <<= 1) {
        int u = (t >= d) ? ps[t - d] : 0;
        __syncthreads();
        ps[t] += u;
        __syncthreads();
    }
    if (t == 255) partials[b] = ps[255];
    int run = (t == 0) ? 0 : ps[t - 1];
#pragma unroll
    for (int q = 0; q < 4; ++q) {
        if (i0 + q < N_CNT) foff[i0 + q] = run;
        run += v[q];
    }
}

// ---------------- scanC: globalize foff (each block reduces needed partials itself);
// zero cur0; sentinel-fill pad slots; last thread writes grand total to foff[N_CNT].
__global__ __launch_bounds__(256) void scanC(int* __restrict__ foff,
                                             const int* __restrict__ partials,
                                             const int* __restrict__ cnt,
                                             int* __restrict__ cur0,
                                             int* __restrict__ sorted) {
    __shared__ int red[256];
    const int b = blockIdx.x, t = threadIdx.x;
    const int pb = b >> 2;                 // this block's 256 i's all live in chunk b>>2
    int s = 0;
    for (int j = t; j < pb; j += 256) s += partials[j];
    red[t] = s;
    __syncthreads();
    for (int d = 128; d > 0; d >>= 1) {
        if (t < d) red[t] += red[t + d];
        __syncthreads();
    }
    const int P = red[0];
    int i = b * 256 + t;
    if (i >= N_CNT) return;
    int base = foff[i] + P;
    foff[i] = base;
    cur0[i] = 0;
    int c = cnt[i];
    int cp = (c + 3) & ~3;
    for (int j = c; j < cp; ++j) sorted[base + j] = N_NODES;
    if (i == N_CNT - 1) foff[N_CNT] = base + cp;
}

// ---------------- scatter src into (rel,tgt)-sorted padded order.
// XCD-ownership partitioned: block class (bid&7) owns tgt range [xcd*12500,(xcd+1)*12500),
// so cur0 atomics + sorted payload writes stay in an XCD-private L2 window (line-merged).
__global__ __launch_bounds__(256) void bucket_kernel(const int* __restrict__ ei,
                                                     const int* __restrict__ foff,
                                                     int* __restrict__ cur0,
                                                     int* __restrict__ sorted) {
    const int xcd = blockIdx.x & 7;
    int t = (blockIdx.x >> 3) * 256 + threadIdx.x;
    if (t >= N_REL * N_EDGES) return;
    int r = t / N_EDGES;
    int e = t - r * N_EDGES;
    int tgt = ei[(size_t)r * 2 * N_EDGES + N_EDGES + e];
    if ((unsigned)(tgt - xcd * NODES_PER_XCD) >= (unsigned)NODES_PER_XCD) return;
    int src = ei[(size_t)r * 2 * N_EDGES + e];
    int i = r * N_NODES + tgt;
    int pos = foff[i] + atomicAdd(&cur0[i], 1);
    sorted[pos] = src;
}

// ---------------- gather: one wave per 4 consecutive (rel,node) pairs.
// Edge lists contiguous & 4-padded: inner loop = 1 uniform int4 (4 srcs) + 4 row gathers.
__global__ __launch_bounds__(256) void gather_kernel(const ushort* __restrict__ xbf,
                                                     const int* __restrict__ sorted,
                                                     const int* __restrict__ foff,
                                                     unsigned int* __restrict__ buf) {
    int wid = (blockIdx.x * 256 + threadIdx.x) >> 6;
    wid = __builtin_amdgcn_readfirstlane(wid);
    const int lane = threadIdx.x & 63;
    const int p0 = wid * 4;
    int f0 = foff[p0], f1 = foff[p0 + 1], f2 = foff[p0 + 2], f3 = foff[p0 + 3], f4 = foff[p0 + 4];
#pragma unroll
    for (int pi = 0; pi < 4; ++pi) {
        int gb = (pi == 0) ? f0 : (pi == 1) ? f1 : (pi == 2) ? f2 : f3;
        int ge = (pi == 0) ? f1 : (pi == 1) ? f2 : (pi == 2) ? f3 : f4;
        float ax = 0.f, ay = 0.f;
        for (int g = gb; g < ge; g += 4) {
            int4 s = *(const int4*)(sorted + g);
            unsigned int u0 = ((const unsigned int*)(xbf + ((size_t)s.x << 7)))[lane];
            unsigned int u1 = ((const unsigned int*)(xbf + ((size_t)s.y << 7)))[lane];
            unsigned int u2 = ((const unsigned int*)(xbf + ((size_t)s.z << 7)))[lane];
            unsigned int u3 = ((const unsigned int*)(xbf + ((size_t)s.w << 7)))[lane];
            ax += __uint_as_float(u0 << 16) + __uint_as_float(u1 << 16)
                + __uint_as_float(u2 << 16) + __uint_as_float(u3 << 16);
            ay += __uint_as_float(u0 & 0xffff0000u) + __uint_as_float(u1 & 0xffff0000u)
                + __uint_as_float(u2 & 0xffff0000u) + __uint_as_float(u3 & 0xffff0000u);
        }
        buf[(size_t)(p0 + pi) * 64 + lane] = ((unsigned int)f2bf(ay) << 16) | f2bf(ax);
    }
}

// ---------------- MFMA GEMM: out[100000][128] = A[100000][640]bf16 @ B[640][128]bf16 + bias
// 128x128 tile, 4 waves (2x2), 16x16x32 mfma. XOR-swizzled LDS (stride 64, chunk^row&7);
// epilogue staged through LDS (stride 132) for fully-coalesced float4 output lines.
__global__ __launch_bounds__(256) void gemm_kernel(const ushort* __restrict__ buf,
                                                   const ushort* __restrict__ xbf,
                                                   const ushort* __restrict__ WbT,
                                                   const int* __restrict__ cnt,
                                                   const float* __restrict__ bias,
                                                   const float* __restrict__ b_sl,
                                                   float* __restrict__ out) {
    __shared__ __align__(16) float SH[64 * 132];   // 33.8 KB: A/B bf16 tiles OR C f32 stage
    __shared__ float degS[4 * 128];
    __shared__ float biasS[4 * 128];
    __shared__ float bslS[128];
    ushort* As = (ushort*)SH;          // [128][64] swizzled
    ushort* Bs = As + 128 * 64;        // [128][64] swizzled

    const int tid = threadIdx.x;
    const int l = tid & 63, w = tid >> 6;
    const int wr = w >> 1, wc = w & 1;
    const int lr = l & 15, lq = l >> 4;
    const int n0 = blockIdx.x * 128;

#pragma unroll
    for (int it = 0; it < 2; ++it) {
        int idx = it * 256 + tid;
        int r = idx >> 7, row = idx & 127;
        int n = n0 + row;
        degS[idx] = (n < N_NODES) ? (float)cnt[r * N_NODES + n] : 0.f;
        biasS[idx] = bias[idx];
    }
    if (tid < 128) bslS[tid] = b_sl[tid];

    f32x4 acc[4][4];
#pragma unroll
    for (int mi = 0; mi < 4; ++mi)
#pragma unroll
        for (int ni = 0; ni < 4; ++ni) acc[mi][ni] = (f32x4){0.f, 0.f, 0.f, 0.f};

    for (int kt = 0; kt < 10; ++kt) {
        __syncthreads();   // LDS free (prev readers done); kt==0 also covers deg/bias staging
        const int region = kt >> 1;
        const int d0 = (kt & 1) * 64;
#pragma unroll
        for (int it = 0; it < 4; ++it) {
            int id = it * 256 + tid;
            int r_ = id >> 3, c16 = id & 7;
            int n = n0 + r_;
            if (n > N_NODES - 1) n = N_NODES - 1;   // clamp keeps loads in-bounds
            const ushort* sp = (region < 4)
                ? (buf + (((size_t)region * N_NODES + n) << 7) + d0)
                : (xbf + ((size_t)n << 7) + d0);
            int4 va = *(const int4*)(sp + c16 * 8);
            *(int4*)(As + r_ * 64 + ((c16 ^ (r_ & 7)) << 3)) = va;
            int4 vb = *(const int4*)(WbT + (size_t)r_ * 640 + kt * 64 + c16 * 8);
            *(int4*)(Bs + r_ * 64 + ((c16 ^ (r_ & 7)) << 3)) = vb;
        }
        __syncthreads();
#pragma unroll
        for (int ks = 0; ks < 2; ++ks) {
            const int ch = ks * 4 + lq;
            const int chs = (ch ^ (lr & 7)) << 3;
            bf16x8 a[4], bb[4];
#pragma unroll
            for (int mi = 0; mi < 4; ++mi)
                a[mi] = *(const bf16x8*)(As + (wr * 64 + mi * 16 + lr) * 64 + chs);
#pragma unroll
            for (int ni = 0; ni < 4; ++ni)
                bb[ni] = *(const bf16x8*)(Bs + (wc * 64 + ni * 16 + lr) * 64 + chs);
#pragma unroll
            for (int mi = 0; mi < 4; ++mi)
#pragma unroll
                for (int ni = 0; ni < 4; ++ni)
                    acc[mi][ni] = __builtin_amdgcn_mfma_f32_16x16x32_bf16(a[mi], bb[ni], acc[mi][ni], 0, 0, 0);
        }
    }

    // epilogue: frag layout col=lane&15, row=(lane>>4)*4+q. Stage through LDS, float4 out.
    float bw[4][4], bsl_[4];
#pragma unroll
    for (int ni = 0; ni < 4; ++ni) {
        int f = wc * 64 + ni * 16 + lr;
        bsl_[ni] = bslS[f];
#pragma unroll
        for (int r = 0; r < 4; ++r) bw[ni][r] = biasS[r * 128 + f];
    }
    float* Cs = SH;   // [64][132]
#pragma unroll
    for (int h = 0; h < 2; ++h) {
        __syncthreads();   // A/B tile (or prev half) readers done
        if (wr == h) {
#pragma unroll
            for (int mi = 0; mi < 4; ++mi)
#pragma unroll
                for (int q = 0; q < 4; ++q) {
                    int row = mi * 16 + lq * 4 + q;          // 0..63
                    int gr = h * 64 + row;
                    float d0_ = degS[gr], d1_ = degS[128 + gr], d2_ = degS[256 + gr], d3_ = degS[384 + gr];
#pragma unroll
                    for (int ni = 0; ni < 4; ++ni) {
                        int f = wc * 64 + ni * 16 + lr;
                        Cs[row * 132 + f] = acc[mi][ni][q] + d0_ * bw[ni][0] + d1_ * bw[ni][1]
                                          + d2_ * bw[ni][2] + d3_ * bw[ni][3] + bsl_[ni];
                    }
                }
        }
        __syncthreads();
#pragma unroll
        for (int it = 0; it < 8; ++it) {
            int idx = it * 256 + tid;        // 0..2047
            int row = idx >> 5, c4 = idx & 31;
            int n = n0 + h * 64 + row;
            if (n < N_NODES)
                *(float4*)(out + (size_t)n * 128 + c4 * 4) = *(const float4*)(Cs + row * 132 + c4 * 4);
        }
    }
}

extern "C" void kernel_launch(void* const* d_in, const int* in_sizes, int n_in,
                              void* d_out, int out_size, void* d_ws, size_t ws_size,
                              hipStream_t stream) {
    const float* x    = (const float*)d_in[0];
    const int*   ei   = (const int*)d_in[1];
    const float* W    = (const float*)d_in[2];
    const float* b    = (const float*)d_in[3];
    const float* W_sl = (const float*)d_in[4];
    const float* b_sl = (const float*)d_in[5];
    float* out = (float*)d_out;

    // ws layout (~148 MB), 256B-aligned chunks
    int*          cnt      = (int*)d_ws;                          // 400000
    int*          cur0     = cnt + N_CNT;                         // 400000
    int*          foff     = cur0 + N_CNT;                        // 400001 (+pad)
    int*          partials = foff + N_CNT + 64;                   // 391 (+pad)
    ushort*       WbT      = (ushort*)(partials + 512);           // 128*640
    ushort*       xbf      = WbT + 128 * 640;                     // (100001)*128
    int*          sorted   = (int*)(xbf + (size_t)(N_NODES + 1) * D + 64);  // up to 3.2M
    unsigned int* buf      = (unsigned int*)(sorted + SORT_MAX);  // 400000*64 uints

    hipMemsetAsync(cnt, 0, N_CNT * sizeof(int), stream);

    prep_kernel<<<CVT_BLOCKS + WB_BLOCKS + ZR_BLOCKS + HIST_BLOCKS, 256, 0, stream>>>(
        x, ei, W, W_sl, xbf, WbT, cnt);
    scanA<<<N_SCAN_BLK, 256, 0, stream>>>(cnt, foff, partials);
    scanC<<<(N_CNT + 255) / 256, 256, 0, stream>>>(foff, partials, cnt, cur0, sorted);
    bucket_kernel<<<((N_REL * N_EDGES + 255) / 256) * NXCD, 256, 0, stream>>>(ei, foff, cur0, sorted);
    gather_kernel<<<N_CNT / 16, 256, 0, stream>>>(xbf, sorted, foff, buf);
    gemm_kernel<<<(N_NODES + 127) / 128, 256, 0, stream>>>((const ushort*)buf, xbf, WbT, cnt, b, b_sl, out);
}